// Round 1
// baseline (15475.893 us; speedup 1.0000x reference)
//
#include <hip/hip_runtime.h>

// ---------------------------------------------------------------------------
// KIT-LSTM  (BS=256, TS=512, I=128, H=256, S=32, ONT=20)
//
// Phase A (parallel): transpose + precompute 8 bf16 "streams" per (t,b):
//   g0..g3: W_{ii,if,ig,io}@x + (b_i*+b_h*)      g4: W_ic@x + b_ic + b_hc
//   g5: sigmoid(W_g@(1+e^-dx) + b_g)             g6: sigmoid(W_k@a + b_k)
//   g7: W_pc@p + b_pc
//   plus a_t (output 3) and g2 = sigmoid(1/d3).
// Phase B (sequential): persistent kernel, 16 WGs x 16 batch columns, no
//   inter-WG communication. Per step: (1536x256)@(256x16) bf16 MFMA
//   (rows 0..1279 consume h, rows 1280..1535 = W_d consume c) + gate combine.
// Head: W_y @ [h_sum; static] -> batchnorm over batch -> sigmoid.
// ---------------------------------------------------------------------------

typedef float        f32x4  __attribute__((ext_vector_type(4)));
typedef short        bf16x8 __attribute__((ext_vector_type(8)));
typedef unsigned short u16x4 __attribute__((ext_vector_type(4)));
typedef unsigned short ushort_t;

#define HD   256
#define BSZ  256
#define TSZ  512
#define IDIM 128
#define NONT 20

__device__ __forceinline__ float b2f(ushort_t u) {
    unsigned int v = ((unsigned int)u) << 16;
    float f; __builtin_memcpy(&f, &v, 4); return f;
}
__device__ __forceinline__ ushort_t f2b(float f) {
    unsigned int v; __builtin_memcpy(&v, &f, 4);
    unsigned int r = (v + 0x7FFFu + ((v >> 16) & 1u)) >> 16;   // RNE
    return (ushort_t)r;
}
__device__ __forceinline__ float sigf(float x) { return 1.f / (1.f + __expf(-x)); }
__device__ __forceinline__ float tanh_f(float x) {
    float e = __expf(-2.f * fabsf(x));
    float t = (1.f - e) / (1.f + e);
    return copysignf(t, x);
}

// ---------------------------------------------------------------------------
// prep: cast/concat weights to bf16, merge bias pairs.
//   Wx [1280][128] rows = {W_ii,W_if,W_ig,W_io,W_ic}; Wg [256][128]
//   Wh [1536][256] rows = {W_hi,W_hf,W_hg,W_ho,W_hc,W_d}
//   bias5[1280] = b_i* + b_h*
// ---------------------------------------------------------------------------
__global__ void prep_kernel(
    const float* __restrict__ W_ii, const float* __restrict__ W_if,
    const float* __restrict__ W_ig, const float* __restrict__ W_io,
    const float* __restrict__ W_ic, const float* __restrict__ W_gm,
    const float* __restrict__ W_hi, const float* __restrict__ W_hf,
    const float* __restrict__ W_hg, const float* __restrict__ W_ho,
    const float* __restrict__ W_hc, const float* __restrict__ W_dm,
    const float* __restrict__ b_ii, const float* __restrict__ b_if,
    const float* __restrict__ b_ig, const float* __restrict__ b_io,
    const float* __restrict__ b_hi, const float* __restrict__ b_hf,
    const float* __restrict__ b_hg, const float* __restrict__ b_ho,
    const float* __restrict__ b_ic, const float* __restrict__ b_hc,
    ushort_t* __restrict__ Wx, ushort_t* __restrict__ Wg,
    ushort_t* __restrict__ Wh, float* __restrict__ bias5)
{
    const int i = blockIdx.x * 256 + threadIdx.x;
    if (i < 1280 * IDIM) {
        int m = i >> 7, k = i & 127, g = m >> 8, rr = m & 255;
        const float* src = (g == 0) ? W_ii : (g == 1) ? W_if : (g == 2) ? W_ig : (g == 3) ? W_io : W_ic;
        Wx[i] = f2b(src[rr * IDIM + k]);
    }
    if (i < 256 * IDIM) Wg[i] = f2b(W_gm[i]);
    if (i < 1536 * HD) {
        int m = i >> 8, k = i & 255, g = m >> 8, rr = m & 255;
        const float* src = (g == 0) ? W_hi : (g == 1) ? W_hf : (g == 2) ? W_hg
                          : (g == 3) ? W_ho : (g == 4) ? W_hc : W_dm;
        Wh[i] = f2b(src[rr * HD + k]);
    }
    if (i < 1280) {
        int g = i >> 8, rr = i & 255;
        const float* sa = (g == 0) ? b_ii : (g == 1) ? b_if : (g == 2) ? b_ig : (g == 3) ? b_io : b_ic;
        const float* sb = (g == 0) ? b_hi : (g == 1) ? b_hf : (g == 2) ? b_hg : (g == 3) ? b_ho : b_hc;
        bias5[i] = sa[rr] + sb[rr];
    }
}

// ---------------------------------------------------------------------------
// init recurrent state: h = 1, c = 1, h_sum = 0
// ---------------------------------------------------------------------------
__global__ void init_kernel(ushort_t* __restrict__ hM, float* __restrict__ cM,
                            float* __restrict__ hsM)
{
    const int i = blockIdx.x * 256 + threadIdx.x;   // 65536
    hM[i] = 0x3F80;   // bf16 1.0
    cM[i] = 1.f;
    hsM[i] = 0.f;
}

// ---------------------------------------------------------------------------
// ont_dist_normed = softmax(|ent - tgt|) -> out[256..276)
// ---------------------------------------------------------------------------
__global__ void ont_kernel(const float* __restrict__ emb, float* __restrict__ o)
{
    __shared__ float dS[NONT];
    const int L = threadIdx.x;
    if (L < NONT) dS[L] = fabsf(emb[L] - emb[NONT]);
    __syncthreads();
    if (L < NONT) {
        float mx = dS[0];
        for (int k = 1; k < NONT; ++k) mx = fmaxf(mx, dS[k]);
        float s = 0.f;
        for (int k = 0; k < NONT; ++k) s += __expf(dS[k] - mx);
        o[L] = __expf(dS[L] - mx) / s;
    }
}

// ---------------------------------------------------------------------------
// transpose/precompute per chunk: n = t_local*256 + b
//   XB[n][128] = bf16(x[b][T0+t][:])       IB[n][128] = bf16(1 + e^-dx)
//   PB[n][20]  = bf16(binary_x)            g2B[n]     = sigmoid(1/d3)
// ---------------------------------------------------------------------------
__global__ void trans_kernel(
    const float* __restrict__ x, const float* __restrict__ dx,
    const float* __restrict__ bx, const float* __restrict__ d3,
    ushort_t* __restrict__ XB, ushort_t* __restrict__ IB,
    ushort_t* __restrict__ PB, float* __restrict__ g2B, int T0)
{
    const int n = blockIdx.x;
    const int t = n >> 8, b = n & 255;
    const int k = threadIdx.x;                       // 128
    const size_t src = ((size_t)b * TSZ + (T0 + t)) * IDIM + k;
    XB[n * IDIM + k] = f2b(x[src]);
    IB[n * IDIM + k] = f2b(1.f + __expf(-dx[src]));
    if (k < NONT) PB[n * NONT + k] = f2b(bx[((size_t)b * TSZ + (T0 + t)) * NONT + k]);
    if (k == 0) g2B[n] = sigf(1.f / d3[(size_t)b * TSZ + (T0 + t)]);
}

// ---------------------------------------------------------------------------
// small mats: per n: a = softmax(ent*p) -> output3;  S[g6] = sigmoid(W_k@a+b_k)
//   S[g7] = W_pc@p + b_pc.   S layout: (((t*8+g)*256 + b)*256 + r), bf16.
// ---------------------------------------------------------------------------
__global__ void small_kernel(
    const ushort_t* __restrict__ PB, const float* __restrict__ emb,
    const float* __restrict__ W_k, const float* __restrict__ b_k,
    const float* __restrict__ W_pc, const float* __restrict__ b_pc,
    ushort_t* __restrict__ S, float* __restrict__ aout, int T0)
{
    const int n = blockIdx.x;
    const int t = n >> 8, b = n & 255;
    const int L = threadIdx.x;                        // 64
    __shared__ float pS[NONT], aS[NONT];
    if (L < NONT) pS[L] = b2f(PB[n * NONT + L]);
    __syncthreads();
    if (L < NONT) aS[L] = emb[L] * pS[L];
    __syncthreads();
    float aval = 0.f;
    {
        float mx = aS[0];
        #pragma unroll
        for (int k = 1; k < NONT; ++k) mx = fmaxf(mx, aS[k]);
        float sum = 0.f;
        #pragma unroll
        for (int k = 0; k < NONT; ++k) sum += __expf(aS[k] - mx);
        if (L < NONT) aval = __expf(aS[L] - mx) / sum;
    }
    __syncthreads();
    if (L < NONT) {
        aS[L] = aval;
        aout[(size_t)L * (TSZ * BSZ) + (size_t)T0 * BSZ + n] = aval;
    }
    __syncthreads();
    #pragma unroll
    for (int j = 0; j < 4; ++j) {
        int rr = j * 64 + L;
        float accK = b_k[rr], accP = b_pc[rr];
        #pragma unroll
        for (int k = 0; k < NONT; ++k) {
            accK += W_k[rr * NONT + k] * aS[k];
            accP += W_pc[rr * NONT + k] * pS[k];
        }
        S[(((size_t)t * 8 + 6) * 256 + b) * 256 + rr] = f2b(sigf(accK));
        S[(((size_t)t * 8 + 7) * 256 + b) * 256 + rr] = f2b(accP);
    }
}

// ---------------------------------------------------------------------------
// Phase-A GEMM: 128x128 tiles, bf16 MFMA 16x16x32, K=128.
//   mt 0..9 : gates (A = Wx, B = XB, +bias5)       mt 10..11 : G (A = Wg,
//   B = IB, sigmoid(+b_g)).  Writes S planes g0..g5.
// LDS tiles stored [row][k] with 16B-granule XOR swizzle (2-way max).
// ---------------------------------------------------------------------------
__launch_bounds__(256)
__global__ void gemmA_kernel(
    const ushort_t* __restrict__ Wx, const ushort_t* __restrict__ Wg,
    const ushort_t* __restrict__ XB, const ushort_t* __restrict__ IB,
    const float* __restrict__ bias5, const float* __restrict__ b_g,
    ushort_t* __restrict__ S)
{
    const int mt = blockIdx.x;                 // 0..11
    const int nt = blockIdx.y;                 // 0..2C-1
    const bool isG = (mt >= 10);
    const ushort_t* A = isG ? (Wg + (size_t)(mt - 10) * 128 * IDIM)
                            : (Wx + (size_t)mt * 128 * IDIM);
    const ushort_t* B = (isG ? IB : XB) + (size_t)nt * 128 * IDIM;

    __shared__ ushort_t Asm[128 * 128];
    __shared__ ushort_t Bsm[128 * 128];

    const int tid = threadIdx.x;
    const int lane = tid & 63, w = tid >> 6;
    const int l15 = lane & 15, l4 = lane >> 4;

    {
        const int4* As = (const int4*)A;
        const int4* Bs = (const int4*)B;
        int4* Ad = (int4*)Asm;
        int4* Bd = (int4*)Bsm;
        #pragma unroll
        for (int c = 0; c < 8; ++c) {
            int idx = c * 256 + tid;               // 0..2047 (16B units)
            int row = idx >> 4, kb = idx & 15;
            int didx = row * 16 + (kb ^ (row & 7));
            Ad[didx] = As[idx];
            Bd[didx] = Bs[idx];
        }
    }
    __syncthreads();

    const int wm = (w >> 1) * 64, wn = (w & 1) * 64;
    f32x4 acc[4][4];
    #pragma unroll
    for (int i = 0; i < 4; ++i) {
        #pragma unroll
        for (int j = 0; j < 4; ++j) acc[i][j] = (f32x4){0.f, 0.f, 0.f, 0.f};
    }

    #pragma unroll
    for (int ks = 0; ks < 4; ++ks) {
        bf16x8 af[4], bfr[4];
        #pragma unroll
        for (int fi = 0; fi < 4; ++fi) {
            int rowA = wm + fi * 16 + l15;
            af[fi] = ((const bf16x8*)Asm)[rowA * 16 + ((ks * 4 + l4) ^ (rowA & 7))];
            int rowB = wn + fi * 16 + l15;
            bfr[fi] = ((const bf16x8*)Bsm)[rowB * 16 + ((ks * 4 + l4) ^ (rowB & 7))];
        }
        #pragma unroll
        for (int fi = 0; fi < 4; ++fi) {
            #pragma unroll
            for (int fj = 0; fj < 4; ++fj)
                acc[fi][fj] = __builtin_amdgcn_mfma_f32_16x16x32_bf16(af[fi], bfr[fj], acc[fi][fj], 0, 0, 0);
        }
    }

    // epilogue: C row = (lane>>4)*4 + i, col = lane&15  (m89-verified)
    const int t = nt >> 1;
    const int bbase = (nt & 1) * 128 + wn;
    #pragma unroll
    for (int fi = 0; fi < 4; ++fi) {
        #pragma unroll
        for (int fj = 0; fj < 4; ++fj) {
            int b = bbase + fj * 16 + l15;
            int mrow = wm + fi * 16 + l4 * 4;
            float v[4];
            int gate, rr;
            if (!isG) {
                int m = mt * 128 + mrow;
                gate = m >> 8; rr = m & 255;
                #pragma unroll
                for (int i = 0; i < 4; ++i) v[i] = acc[fi][fj][i] + bias5[m + i];
            } else {
                rr = (mt - 10) * 128 + mrow;
                gate = 5;
                #pragma unroll
                for (int i = 0; i < 4; ++i) v[i] = sigf(acc[fi][fj][i] + b_g[rr + i]);
            }
            u16x4 pk;
            #pragma unroll
            for (int i = 0; i < 4; ++i) pk[i] = f2b(v[i]);
            *(u16x4*)&S[(((size_t)t * 8 + gate) * 256 + b) * 256 + rr] = pk;
        }
    }
}

// ---------------------------------------------------------------------------
// Phase B: persistent recurrence. 16 blocks x 256 threads, block owns 16
// batch columns. Per step: 96 MFMA M-tiles (24/wave, 2-way ILP) with A
// streamed from L2, B = h (bf16, XOR-swizzled LDS) or c; then per-thread
// (r=tid) gate combine over 16 columns. c, h_sum live in f32 registers.
// ---------------------------------------------------------------------------
__launch_bounds__(256, 1)
__global__ void phaseB_kernel(
    const ushort_t* __restrict__ Wh, const ushort_t* __restrict__ S,
    const float* __restrict__ g2B, const float* __restrict__ b_d,
    ushort_t* __restrict__ hM, float* __restrict__ cM,
    float* __restrict__ hsM, int C)
{
    __shared__ float    P[1536 * 17];       // preacts, pad-17 (conflict-free)
    __shared__ ushort_t hB[16 * 256];       // h bf16, [nn][k] XOR-swizzled
    __shared__ ushort_t cB[16 * 256];       // c bf16
    __shared__ float    g2s[16];

    const int tid = threadIdx.x;
    const int lane = tid & 63, w = tid >> 6;
    const int l15 = lane & 15, l4 = lane >> 4;
    const int b0 = blockIdx.x * 16;
    const int r = tid;

    float c_reg[16], hs[16];
    const float bdr = b_d[r];

    #pragma unroll
    for (int nn = 0; nn < 16; ++nn) {
        hB[nn * 256 + (r ^ ((nn & 7) << 3))] = hM[(b0 + nn) * HD + r];
        float cv = cM[(b0 + nn) * HD + r];
        c_reg[nn] = cv;
        cB[nn * 256 + (r ^ ((nn & 7) << 3))] = f2b(cv);
        hs[nn] = hsM[r * BSZ + b0 + nn];
    }
    __syncthreads();

    for (int t = 0; t < C; ++t) {
        if (tid < 16) g2s[tid] = g2B[t * BSZ + b0 + tid];

        // ---- MFMA: preacts for all 1536 rows, K=256 ----
        #pragma unroll 1
        for (int p = 0; p < 12; ++p) {
            const int mtA = w * 24 + p, mtB = mtA + 12;
            const ushort_t* bsA = (mtA >= 80) ? cB : hB;
            const ushort_t* bsB = (mtB >= 80) ? cB : hB;
            const bf16x8* wa = (const bf16x8*)(Wh + (size_t)(mtA * 16 + l15) * HD) + l4;
            const bf16x8* wb = (const bf16x8*)(Wh + (size_t)(mtB * 16 + l15) * HD) + l4;
            f32x4 acc0 = (f32x4){0.f, 0.f, 0.f, 0.f};
            f32x4 acc1 = (f32x4){0.f, 0.f, 0.f, 0.f};
            #pragma unroll
            for (int ks = 0; ks < 8; ++ks) {
                bf16x8 a0 = wa[ks * 4];
                bf16x8 a1 = wb[ks * 4];
                const int bi = l15 * 32 + ((ks * 4 + l4) ^ (l15 & 7));
                bf16x8 bv0 = ((const bf16x8*)bsA)[bi];
                bf16x8 bv1 = ((const bf16x8*)bsB)[bi];
                acc0 = __builtin_amdgcn_mfma_f32_16x16x32_bf16(a0, bv0, acc0, 0, 0, 0);
                acc1 = __builtin_amdgcn_mfma_f32_16x16x32_bf16(a1, bv1, acc1, 0, 0, 0);
            }
            #pragma unroll
            for (int i = 0; i < 4; ++i) {
                P[(mtA * 16 + l4 * 4 + i) * 17 + l15] = acc0[i];
                P[(mtB * 16 + l4 * 4 + i) * 17 + l15] = acc1[i];
            }
        }
        __syncthreads();

        // ---- combine: thread owns h-row r for 16 columns ----
        const ushort_t* St = S + (size_t)t * 524288 + r;
        #pragma unroll
        for (int nn = 0; nn < 16; ++nn) {
            const ushort_t* Sb = St + (size_t)(b0 + nn) * 256;
            float s0 = b2f(Sb[0 * 65536]);
            float s1 = b2f(Sb[1 * 65536]);
            float s2 = b2f(Sb[2 * 65536]);
            float s3 = b2f(Sb[3 * 65536]);
            float s4 = b2f(Sb[4 * 65536]);
            float s5 = b2f(Sb[5 * 65536]);
            float s6 = b2f(Sb[6 * 65536]);
            float s7 = b2f(Sb[7 * 65536]);
            float pi  = P[(0 * HD + r) * 17 + nn];
            float pf  = P[(1 * HD + r) * 17 + nn];
            float pg  = P[(2 * HD + r) * 17 + nn];
            float po  = P[(3 * HD + r) * 17 + nn];
            float pkg = P[(4 * HD + r) * 17 + nn];
            float pcs = P[(5 * HD + r) * 17 + nn];
            float it   = sigf(s0 + pi);
            float ft   = sigf(s1 + pf);
            float cand = tanh_f(s2 + pg);
            float ot   = sigf(s3 + po);
            float kg   = tanh_f(s4 + s7 + pkg);
            float cs   = tanh_f(pcs + bdr);
            float g2   = g2s[nn];
            float cold = c_reg[nn];
            float cstar = (cold - cs) * s5 + cs * g2;
            float cnew  = ft * cstar + it * cand + s6 * kg;
            float hnew  = ot * tanh_f(cnew);
            hs[nn] += hnew;
            c_reg[nn] = cnew;
            hB[nn * 256 + (r ^ ((nn & 7) << 3))] = f2b(hnew);
            cB[nn * 256 + (r ^ ((nn & 7) << 3))] = f2b(cnew);
        }
        __syncthreads();
    }

    #pragma unroll
    for (int nn = 0; nn < 16; ++nn) {
        hM[(b0 + nn) * HD + r] = hB[nn * 256 + (r ^ ((nn & 7) << 3))];
        cM[(b0 + nn) * HD + r] = c_reg[nn];
        hsM[r * BSZ + b0 + nn] = hs[nn];
    }
}

// ---------------------------------------------------------------------------
// head: out[b] = W_y @ [h_sum[:,b]; static[b,:]] + b_y -> batchnorm -> sigmoid
// ---------------------------------------------------------------------------
__global__ void head_kernel(
    const float* __restrict__ W_y, const float* __restrict__ b_y,
    const float* __restrict__ sx, const float* __restrict__ hsM,
    const float* __restrict__ gamma, const float* __restrict__ beta,
    float* __restrict__ yout)
{
    const int b = threadIdx.x;   // 256
    float acc = b_y[0];
    for (int rr = 0; rr < HD; ++rr) acc += W_y[rr] * hsM[rr * BSZ + b];
    #pragma unroll
    for (int s = 0; s < 32; ++s) acc += W_y[HD + s] * sx[b * 32 + s];

    __shared__ float red[256];
    red[b] = acc; __syncthreads();
    for (int st = 128; st > 0; st >>= 1) {
        if (b < st) red[b] += red[b + st];
        __syncthreads();
    }
    float mean = red[0] * (1.f / 256.f);
    __syncthreads();
    float d = acc - mean;
    red[b] = d * d; __syncthreads();
    for (int st = 128; st > 0; st >>= 1) {
        if (b < st) red[b] += red[b + st];
        __syncthreads();
    }
    float var = red[0] * (1.f / 256.f);
    yout[b] = sigf(d * rsqrtf(var + 1e-5f) * gamma[0] + beta[0]);
}

// ---------------------------------------------------------------------------
extern "C" void kernel_launch(void* const* d_in, const int* in_sizes, int n_in,
                              void* d_out, int out_size, void* d_ws, size_t ws_size,
                              hipStream_t stream)
{
    (void)in_sizes; (void)n_in; (void)out_size;
    const float* x    = (const float*)d_in[0];
    const float* dxp  = (const float*)d_in[1];
    const float* bx   = (const float*)d_in[2];
    const float* sx   = (const float*)d_in[3];
    const float* d3   = (const float*)d_in[4];
    const float* W_ii = (const float*)d_in[9];
    const float* W_if = (const float*)d_in[10];
    const float* W_ig = (const float*)d_in[11];
    const float* W_io = (const float*)d_in[12];
    const float* W_hi = (const float*)d_in[13];
    const float* W_hf = (const float*)d_in[14];
    const float* W_hg = (const float*)d_in[15];
    const float* W_ho = (const float*)d_in[16];
    const float* b_ii = (const float*)d_in[17];
    const float* b_if = (const float*)d_in[18];
    const float* b_ig = (const float*)d_in[19];
    const float* b_io = (const float*)d_in[20];
    const float* b_hi = (const float*)d_in[21];
    const float* b_hf = (const float*)d_in[22];
    const float* b_hg = (const float*)d_in[23];
    const float* b_ho = (const float*)d_in[24];
    const float* W_y  = (const float*)d_in[25];
    const float* b_y  = (const float*)d_in[26];
    const float* W_d  = (const float*)d_in[27];
    const float* b_d  = (const float*)d_in[28];
    const float* W_g  = (const float*)d_in[29];
    const float* b_g  = (const float*)d_in[30];
    const float* W_ic = (const float*)d_in[31];
    const float* W_hc = (const float*)d_in[32];
    const float* W_pc = (const float*)d_in[33];
    const float* b_ic = (const float*)d_in[34];
    const float* b_hc = (const float*)d_in[35];
    const float* b_pc = (const float*)d_in[36];
    const float* W_k  = (const float*)d_in[37];
    const float* b_k  = (const float*)d_in[38];
    const float* emb  = (const float*)d_in[39];
    const float* gam  = (const float*)d_in[40];
    const float* bet  = (const float*)d_in[41];
    float* out = (float*)d_out;

    char* base = (char*)d_ws;
    size_t off = 0;
    auto take = [&](size_t bytes) -> char* {
        char* p = base + off;
        off = (off + bytes + 255) & ~(size_t)255;
        return p;
    };
    ushort_t* Wx    = (ushort_t*)take((size_t)1280 * 128 * 2);
    ushort_t* Wg    = (ushort_t*)take((size_t)256 * 128 * 2);
    ushort_t* Wh    = (ushort_t*)take((size_t)1536 * 256 * 2);
    float*    bias5 = (float*)take(1280 * 4);
    ushort_t* hM    = (ushort_t*)take((size_t)65536 * 2);
    float*    cM    = (float*)take((size_t)65536 * 4);
    float*    hsM   = (float*)take((size_t)65536 * 4);
    size_t fixedOff = off;

    // per-step chunk bytes: XB 65536 + IB 65536 + PB 10240 + g2B 1024 + S 1048576
    int C = 512;
    while (C > 4) {
        size_t need = fixedOff + (size_t)C * (65536 + 65536 + 10240 + 1024 + 1048576) + 6 * 256;
        if (need <= ws_size) break;
        C >>= 1;
    }
    ushort_t* XB  = (ushort_t*)take((size_t)C * 65536);
    ushort_t* IB  = (ushort_t*)take((size_t)C * 65536);
    ushort_t* PB  = (ushort_t*)take((size_t)C * 10240);
    float*    g2B = (float*)take((size_t)C * 1024);
    ushort_t* S   = (ushort_t*)take((size_t)C * 1048576);

    prep_kernel<<<1536, 256, 0, stream>>>(
        W_ii, W_if, W_ig, W_io, W_ic, W_g, W_hi, W_hf, W_hg, W_ho, W_hc, W_d,
        b_ii, b_if, b_ig, b_io, b_hi, b_hf, b_hg, b_ho, b_ic, b_hc,
        Wx, Wg, Wh, bias5);
    ont_kernel<<<1, 64, 0, stream>>>(emb, out + 256);
    init_kernel<<<256, 256, 0, stream>>>(hM, cM, hsM);

    for (int T0 = 0; T0 < TSZ; T0 += C) {
        trans_kernel<<<C * 256, 128, 0, stream>>>(x, dxp, bx, d3, XB, IB, PB, g2B, T0);
        small_kernel<<<C * 256, 64, 0, stream>>>(PB, emb, W_k, b_k, W_pc, b_pc, S, out + 276, T0);
        gemmA_kernel<<<dim3(12, C * 2), 256, 0, stream>>>(Wx, Wg, XB, IB, bias5, b_g, S);
        phaseB_kernel<<<16, 256, 0, stream>>>(Wh, S, g2B, b_d, hM, cM, hsM, C);
    }
    head_kernel<<<1, 256, 0, stream>>>(W_y, b_y, sx, hsM, gam, bet, out);
}

// Round 3
// 10502.028 us; speedup vs baseline: 1.4736x; 1.4736x over previous
//
#include <hip/hip_runtime.h>

// ---------------------------------------------------------------------------
// KIT-LSTM  (BS=256, TS=512, I=128, H=256, S=32, ONT=20)
//
// Phase A (parallel): transpose + precompute 8 bf16 "streams" per (t,b).
// Phase B (sequential): persistent kernel, 16 WGs x 512 threads (8 waves,
//   2 waves/SIMD), block owns 16 batch columns. Wave w owns row-tiles
//   {2w,2w+1} x all 6 gates (12 MFMA tiles) so the gate combine is fully
//   in-register (no P LDS array). Wh streamed from L2 via 12 base pointers
//   + imm offsets, 1:1 load:MFMA over 12 independent acc chains.
// Head: W_y @ [h_sum; static] -> batchnorm over batch -> sigmoid.
// ---------------------------------------------------------------------------

typedef float        f32x4  __attribute__((ext_vector_type(4)));
typedef short        bf16x8 __attribute__((ext_vector_type(8)));
typedef unsigned short u16x4 __attribute__((ext_vector_type(4)));
typedef unsigned short ushort_t;

#define HD   256
#define BSZ  256
#define TSZ  512
#define IDIM 128
#define NONT 20

__device__ __forceinline__ float b2f(ushort_t u) {
    unsigned int v = ((unsigned int)u) << 16;
    float f; __builtin_memcpy(&f, &v, 4); return f;
}
__device__ __forceinline__ ushort_t f2b(float f) {
    unsigned int v; __builtin_memcpy(&v, &f, 4);
    unsigned int r = (v + 0x7FFFu + ((v >> 16) & 1u)) >> 16;   // RNE
    return (ushort_t)r;
}
__device__ __forceinline__ float rcp_fast(float x) { return __builtin_amdgcn_rcpf(x); }
__device__ __forceinline__ float sigf(float x) { return rcp_fast(1.f + __expf(-x)); }
// tanh(x) = 1 - 2/(e^{2x}+1); overflow-safe (inf -> 1, -inf -> -1)
__device__ __forceinline__ float tanh_f(float x) {
    return __builtin_fmaf(-2.f, rcp_fast(__expf(2.f * x) + 1.f), 1.f);
}

// ---------------------------------------------------------------------------
// prep: cast/concat weights to bf16, merge bias pairs.
//   Wx [1280][128] rows = {W_ii,W_if,W_ig,W_io,W_ic}; Wg [256][128]
//   Wh [1536][256] rows = {W_hi,W_hf,W_hg,W_ho,W_hc,W_d}
//   bias5[1280] = b_i* + b_h*
// ---------------------------------------------------------------------------
__global__ void prep_kernel(
    const float* __restrict__ W_ii, const float* __restrict__ W_if,
    const float* __restrict__ W_ig, const float* __restrict__ W_io,
    const float* __restrict__ W_ic, const float* __restrict__ W_gm,
    const float* __restrict__ W_hi, const float* __restrict__ W_hf,
    const float* __restrict__ W_hg, const float* __restrict__ W_ho,
    const float* __restrict__ W_hc, const float* __restrict__ W_dm,
    const float* __restrict__ b_ii, const float* __restrict__ b_if,
    const float* __restrict__ b_ig, const float* __restrict__ b_io,
    const float* __restrict__ b_hi, const float* __restrict__ b_hf,
    const float* __restrict__ b_hg, const float* __restrict__ b_ho,
    const float* __restrict__ b_ic, const float* __restrict__ b_hc,
    ushort_t* __restrict__ Wx, ushort_t* __restrict__ Wg,
    ushort_t* __restrict__ Wh, float* __restrict__ bias5)
{
    const int i = blockIdx.x * 256 + threadIdx.x;
    if (i < 1280 * IDIM) {
        int m = i >> 7, k = i & 127, g = m >> 8, rr = m & 255;
        const float* src = (g == 0) ? W_ii : (g == 1) ? W_if : (g == 2) ? W_ig : (g == 3) ? W_io : W_ic;
        Wx[i] = f2b(src[rr * IDIM + k]);
    }
    if (i < 256 * IDIM) Wg[i] = f2b(W_gm[i]);
    if (i < 1536 * HD) {
        int m = i >> 8, k = i & 255, g = m >> 8, rr = m & 255;
        const float* src = (g == 0) ? W_hi : (g == 1) ? W_hf : (g == 2) ? W_hg
                          : (g == 3) ? W_ho : (g == 4) ? W_hc : W_dm;
        Wh[i] = f2b(src[rr * HD + k]);
    }
    if (i < 1280) {
        int g = i >> 8, rr = i & 255;
        const float* sa = (g == 0) ? b_ii : (g == 1) ? b_if : (g == 2) ? b_ig : (g == 3) ? b_io : b_ic;
        const float* sb = (g == 0) ? b_hi : (g == 1) ? b_hf : (g == 2) ? b_hg : (g == 3) ? b_ho : b_hc;
        bias5[i] = sa[rr] + sb[rr];
    }
}

// ---------------------------------------------------------------------------
// init recurrent state: h = 1, c = 1, h_sum = 0
// ---------------------------------------------------------------------------
__global__ void init_kernel(ushort_t* __restrict__ hM, float* __restrict__ cM,
                            float* __restrict__ hsM)
{
    const int i = blockIdx.x * 256 + threadIdx.x;   // 65536
    hM[i] = 0x3F80;   // bf16 1.0
    cM[i] = 1.f;
    hsM[i] = 0.f;
}

// ---------------------------------------------------------------------------
// ont_dist_normed = softmax(|ent - tgt|) -> out[256..276)
// ---------------------------------------------------------------------------
__global__ void ont_kernel(const float* __restrict__ emb, float* __restrict__ o)
{
    __shared__ float dS[NONT];
    const int L = threadIdx.x;
    if (L < NONT) dS[L] = fabsf(emb[L] - emb[NONT]);
    __syncthreads();
    if (L < NONT) {
        float mx = dS[0];
        for (int k = 1; k < NONT; ++k) mx = fmaxf(mx, dS[k]);
        float s = 0.f;
        for (int k = 0; k < NONT; ++k) s += __expf(dS[k] - mx);
        o[L] = __expf(dS[L] - mx) / s;
    }
}

// ---------------------------------------------------------------------------
// transpose/precompute per chunk: n = t_local*256 + b
// ---------------------------------------------------------------------------
__global__ void trans_kernel(
    const float* __restrict__ x, const float* __restrict__ dx,
    const float* __restrict__ bx, const float* __restrict__ d3,
    ushort_t* __restrict__ XB, ushort_t* __restrict__ IB,
    ushort_t* __restrict__ PB, float* __restrict__ g2B, int T0)
{
    const int n = blockIdx.x;
    const int t = n >> 8, b = n & 255;
    const int k = threadIdx.x;                       // 128
    const size_t src = ((size_t)b * TSZ + (T0 + t)) * IDIM + k;
    XB[n * IDIM + k] = f2b(x[src]);
    IB[n * IDIM + k] = f2b(1.f + __expf(-dx[src]));
    if (k < NONT) PB[n * NONT + k] = f2b(bx[((size_t)b * TSZ + (T0 + t)) * NONT + k]);
    if (k == 0) g2B[n] = sigf(1.f / d3[(size_t)b * TSZ + (T0 + t)]);
}

// ---------------------------------------------------------------------------
// small mats: per n: a = softmax(ent*p) -> output3;  S[g6] = sigmoid(W_k@a+b_k)
//   S[g7] = W_pc@p + b_pc.   S layout: (((t*8+g)*256 + b)*256 + r), bf16.
// ---------------------------------------------------------------------------
__global__ void small_kernel(
    const ushort_t* __restrict__ PB, const float* __restrict__ emb,
    const float* __restrict__ W_k, const float* __restrict__ b_k,
    const float* __restrict__ W_pc, const float* __restrict__ b_pc,
    ushort_t* __restrict__ S, float* __restrict__ aout, int T0)
{
    const int n = blockIdx.x;
    const int t = n >> 8, b = n & 255;
    const int L = threadIdx.x;                        // 64
    __shared__ float pS[NONT], aS[NONT];
    if (L < NONT) pS[L] = b2f(PB[n * NONT + L]);
    __syncthreads();
    if (L < NONT) aS[L] = emb[L] * pS[L];
    __syncthreads();
    float aval = 0.f;
    {
        float mx = aS[0];
        #pragma unroll
        for (int k = 1; k < NONT; ++k) mx = fmaxf(mx, aS[k]);
        float sum = 0.f;
        #pragma unroll
        for (int k = 0; k < NONT; ++k) sum += __expf(aS[k] - mx);
        if (L < NONT) aval = __expf(aS[L] - mx) / sum;
    }
    __syncthreads();
    if (L < NONT) {
        aS[L] = aval;
        aout[(size_t)L * (TSZ * BSZ) + (size_t)T0 * BSZ + n] = aval;
    }
    __syncthreads();
    #pragma unroll
    for (int j = 0; j < 4; ++j) {
        int rr = j * 64 + L;
        float accK = b_k[rr], accP = b_pc[rr];
        #pragma unroll
        for (int k = 0; k < NONT; ++k) {
            accK += W_k[rr * NONT + k] * aS[k];
            accP += W_pc[rr * NONT + k] * pS[k];
        }
        S[(((size_t)t * 8 + 6) * 256 + b) * 256 + rr] = f2b(sigf(accK));
        S[(((size_t)t * 8 + 7) * 256 + b) * 256 + rr] = f2b(accP);
    }
}

// ---------------------------------------------------------------------------
// Phase-A GEMM: 128x128 tiles, bf16 MFMA 16x16x32, K=128.
// ---------------------------------------------------------------------------
__launch_bounds__(256)
__global__ void gemmA_kernel(
    const ushort_t* __restrict__ Wx, const ushort_t* __restrict__ Wg,
    const ushort_t* __restrict__ XB, const ushort_t* __restrict__ IB,
    const float* __restrict__ bias5, const float* __restrict__ b_g,
    ushort_t* __restrict__ S)
{
    const int mt = blockIdx.x;                 // 0..11
    const int nt = blockIdx.y;                 // 0..2C-1
    const bool isG = (mt >= 10);
    const ushort_t* A = isG ? (Wg + (size_t)(mt - 10) * 128 * IDIM)
                            : (Wx + (size_t)mt * 128 * IDIM);
    const ushort_t* B = (isG ? IB : XB) + (size_t)nt * 128 * IDIM;

    __shared__ ushort_t Asm[128 * 128];
    __shared__ ushort_t Bsm[128 * 128];

    const int tid = threadIdx.x;
    const int lane = tid & 63, w = tid >> 6;
    const int l15 = lane & 15, l4 = lane >> 4;

    {
        const int4* As = (const int4*)A;
        const int4* Bs = (const int4*)B;
        int4* Ad = (int4*)Asm;
        int4* Bd = (int4*)Bsm;
        #pragma unroll
        for (int c = 0; c < 8; ++c) {
            int idx = c * 256 + tid;               // 0..2047 (16B units)
            int row = idx >> 4, kb = idx & 15;
            int didx = row * 16 + (kb ^ (row & 7));
            Ad[didx] = As[idx];
            Bd[didx] = Bs[idx];
        }
    }
    __syncthreads();

    const int wm = (w >> 1) * 64, wn = (w & 1) * 64;
    f32x4 acc[4][4];
    #pragma unroll
    for (int i = 0; i < 4; ++i) {
        #pragma unroll
        for (int j = 0; j < 4; ++j) acc[i][j] = (f32x4){0.f, 0.f, 0.f, 0.f};
    }

    #pragma unroll
    for (int ks = 0; ks < 4; ++ks) {
        bf16x8 af[4], bfr[4];
        #pragma unroll
        for (int fi = 0; fi < 4; ++fi) {
            int rowA = wm + fi * 16 + l15;
            af[fi] = ((const bf16x8*)Asm)[rowA * 16 + ((ks * 4 + l4) ^ (rowA & 7))];
            int rowB = wn + fi * 16 + l15;
            bfr[fi] = ((const bf16x8*)Bsm)[rowB * 16 + ((ks * 4 + l4) ^ (rowB & 7))];
        }
        #pragma unroll
        for (int fi = 0; fi < 4; ++fi) {
            #pragma unroll
            for (int fj = 0; fj < 4; ++fj)
                acc[fi][fj] = __builtin_amdgcn_mfma_f32_16x16x32_bf16(af[fi], bfr[fj], acc[fi][fj], 0, 0, 0);
        }
    }

    // epilogue: C row = (lane>>4)*4 + i, col = lane&15  (m89-verified)
    const int t = nt >> 1;
    const int bbase = (nt & 1) * 128 + wn;
    #pragma unroll
    for (int fi = 0; fi < 4; ++fi) {
        #pragma unroll
        for (int fj = 0; fj < 4; ++fj) {
            int b = bbase + fj * 16 + l15;
            int mrow = wm + fi * 16 + l4 * 4;
            float v[4];
            int gate, rr;
            if (!isG) {
                int m = mt * 128 + mrow;
                gate = m >> 8; rr = m & 255;
                #pragma unroll
                for (int i = 0; i < 4; ++i) v[i] = acc[fi][fj][i] + bias5[m + i];
            } else {
                rr = (mt - 10) * 128 + mrow;
                gate = 5;
                #pragma unroll
                for (int i = 0; i < 4; ++i) v[i] = sigf(acc[fi][fj][i] + b_g[rr + i]);
            }
            u16x4 pk;
            #pragma unroll
            for (int i = 0; i < 4; ++i) pk[i] = f2b(v[i]);
            *(u16x4*)&S[(((size_t)t * 8 + gate) * 256 + b) * 256 + rr] = pk;
        }
    }
}

// ---------------------------------------------------------------------------
// Phase B: persistent recurrence. 16 blocks x 512 threads (8 waves =
// 2 waves/SIMD). Wave w owns row-tiles {2w, 2w+1} x 6 gates = 12 MFMA tiles
// -> all 6 gate preacts for lane's (r, nn) pairs land in the lane's own
// accumulators; gate combine is fully in-register (no P LDS).
// Lane (l4,l15): r = (2w+j)*16 + l4*4 + i (j=0..1, i=0..3), nn = l15.
// ---------------------------------------------------------------------------
__launch_bounds__(512, 2)
__global__ void phaseB_kernel(
    const ushort_t* __restrict__ Wh, const ushort_t* __restrict__ S,
    const float* __restrict__ g2B, const float* __restrict__ b_d,
    ushort_t* __restrict__ hM, float* __restrict__ cM,
    float* __restrict__ hsM, int C)
{
    __shared__ ushort_t hB[16 * 256];       // [nn][k], k XOR-swizzled by nn
    __shared__ ushort_t cB[16 * 256];

    const int tid = threadIdx.x;            // 0..511
    const int lane = tid & 63, w = tid >> 6;
    const int l15 = lane & 15, l4 = lane >> 4;
    const int b0 = blockIdx.x * 16;
    const int nn = l15;
    const int rt0 = 2 * w;                  // row-tile pair base
    const int swz = (nn & 7) << 3;

    float c_reg[8], hs[8], bdr[8];

    // ---- load persistent state; fill hB/cB (each lane covers its 8 pairs) ----
    #pragma unroll
    for (int j = 0; j < 2; ++j) {
        const int rbase = (rt0 + j) * 16 + l4 * 4;
        f32x4 cv = *(const f32x4*)&cM[(size_t)(b0 + nn) * HD + rbase];
        u16x4 hv = *(const u16x4*)&hM[(size_t)(b0 + nn) * HD + rbase];
        u16x4 cpk;
        #pragma unroll
        for (int i = 0; i < 4; ++i) {
            c_reg[j * 4 + i] = cv[i];
            cpk[i] = f2b(cv[i]);
            hs[j * 4 + i] = hsM[(size_t)(rbase + i) * BSZ + b0 + nn];
            bdr[j * 4 + i] = b_d[rbase + i];
        }
        const int widx = nn * 256 + (rbase ^ swz);
        *(u16x4*)&hB[widx] = hv;
        *(u16x4*)&cB[widx] = cpk;
    }

    // ---- 12 weight base pointers: tile (g, rt0+j), lane offset l15 row, l4*8 k ----
    const ushort_t* wb[12];
    #pragma unroll
    for (int g = 0; g < 6; ++g)
        #pragma unroll
        for (int j = 0; j < 2; ++j)
            wb[g * 2 + j] = Wh + ((size_t)(g * 256 + (rt0 + j) * 16 + l15) * HD) + l4 * 8;

    // ---- 8 S gate pointers (advanced 1MB bf16 per step) ----
    const ushort_t* sp[8];
    #pragma unroll
    for (int g = 0; g < 8; ++g)
        sp[g] = S + (size_t)g * 65536 + (size_t)(b0 + nn) * 256 + rt0 * 16 + l4 * 4;
    const float* g2p = g2B + b0 + nn;

    __syncthreads();

    #pragma unroll 1
    for (int t = 0; t < C; ++t) {
        // ---- issue S loads first: MFMA phase hides their latency ----
        u16x4 sv[8][2];
        #pragma unroll
        for (int g = 0; g < 8; ++g) {
            sv[g][0] = *(const u16x4*)(sp[g]);
            sv[g][1] = *(const u16x4*)(sp[g] + 16);
            sp[g] += 524288;
        }
        const float g2 = *g2p; g2p += BSZ;

        // ---- MFMA: 12 tiles x K=256, A streamed from L2, B from LDS ----
        f32x4 acc[12];
        #pragma unroll
        for (int gj = 0; gj < 12; ++gj) acc[gj] = (f32x4){0.f, 0.f, 0.f, 0.f};

        #pragma unroll
        for (int ks = 0; ks < 8; ++ks) {
            const int ko = nn * 256 + ((ks * 32 + l4 * 8) ^ swz);
            bf16x8 bh = *(const bf16x8*)&hB[ko];
            bf16x8 bc = *(const bf16x8*)&cB[ko];
            #pragma unroll
            for (int gj = 0; gj < 12; ++gj) {
                bf16x8 a = *(const bf16x8*)(wb[gj] + ks * 32);
                acc[gj] = __builtin_amdgcn_mfma_f32_16x16x32_bf16(
                    a, (gj < 10) ? bh : bc, acc[gj], 0, 0, 0);
            }
        }
        __syncthreads();   // all B reads done before anyone rewrites hB/cB

        // ---- in-register combine: lane's 8 (r,nn) pairs ----
        #pragma unroll
        for (int j = 0; j < 2; ++j) {
            u16x4 hpk, cpk;
            #pragma unroll
            for (int i = 0; i < 4; ++i) {
                const int p = j * 4 + i;
                const float s0 = b2f(sv[0][j][i]);
                const float s1 = b2f(sv[1][j][i]);
                const float s2 = b2f(sv[2][j][i]);
                const float s3 = b2f(sv[3][j][i]);
                const float s4 = b2f(sv[4][j][i]);
                const float s5 = b2f(sv[5][j][i]);
                const float s6 = b2f(sv[6][j][i]);
                const float s7 = b2f(sv[7][j][i]);
                const float it   = sigf(s0 + acc[0 * 2 + j][i]);
                const float ft   = sigf(s1 + acc[1 * 2 + j][i]);
                const float cand = tanh_f(s2 + acc[2 * 2 + j][i]);
                const float ot   = sigf(s3 + acc[3 * 2 + j][i]);
                const float kg   = tanh_f(s4 + s7 + acc[4 * 2 + j][i]);
                const float cs   = tanh_f(acc[5 * 2 + j][i] + bdr[p]);
                const float cold = c_reg[p];
                const float cstar = (cold - cs) * s5 + cs * g2;
                const float cnew  = ft * cstar + it * cand + s6 * kg;
                const float hnew  = ot * tanh_f(cnew);
                hs[p] += hnew;
                c_reg[p] = cnew;
                hpk[i] = f2b(hnew);
                cpk[i] = f2b(cnew);
            }
            const int rbase = (rt0 + j) * 16 + l4 * 4;
            const int widx = nn * 256 + (rbase ^ swz);
            *(u16x4*)&hB[widx] = hpk;
            *(u16x4*)&cB[widx] = cpk;
        }
        __syncthreads();   // writes visible before next step's B reads
    }

    // ---- writeback ----
    #pragma unroll
    for (int j = 0; j < 2; ++j) {
        const int rbase = (rt0 + j) * 16 + l4 * 4;
        const int widx = nn * 256 + (rbase ^ swz);
        *(u16x4*)&hM[(size_t)(b0 + nn) * HD + rbase] = *(const u16x4*)&hB[widx];
        #pragma unroll
        for (int i = 0; i < 4; ++i) {
            cM[(size_t)(b0 + nn) * HD + rbase + i] = c_reg[j * 4 + i];
            hsM[(size_t)(rbase + i) * BSZ + b0 + nn] = hs[j * 4 + i];
        }
    }
}

// ---------------------------------------------------------------------------
// head: out[b] = W_y @ [h_sum[:,b]; static[b,:]] + b_y -> batchnorm -> sigmoid
// ---------------------------------------------------------------------------
__global__ void head_kernel(
    const float* __restrict__ W_y, const float* __restrict__ b_y,
    const float* __restrict__ sx, const float* __restrict__ hsM,
    const float* __restrict__ gamma, const float* __restrict__ beta,
    float* __restrict__ yout)
{
    const int b = threadIdx.x;   // 256
    float acc = b_y[0];
    for (int rr = 0; rr < HD; ++rr) acc += W_y[rr] * hsM[rr * BSZ + b];
    #pragma unroll
    for (int s = 0; s < 32; ++s) acc += W_y[HD + s] * sx[b * 32 + s];

    __shared__ float red[256];
    red[b] = acc; __syncthreads();
    for (int st = 128; st > 0; st >>= 1) {
        if (b < st) red[b] += red[b + st];
        __syncthreads();
    }
    float mean = red[0] * (1.f / 256.f);
    __syncthreads();
    float d = acc - mean;
    red[b] = d * d; __syncthreads();
    for (int st = 128; st > 0; st >>= 1) {
        if (b < st) red[b] += red[b + st];
        __syncthreads();
    }
    float var = red[0] * (1.f / 256.f);
    yout[b] = sigf(d * rsqrtf(var + 1e-5f) * gamma[0] + beta[0]);
}

// ---------------------------------------------------------------------------
extern "C" void kernel_launch(void* const* d_in, const int* in_sizes, int n_in,
                              void* d_out, int out_size, void* d_ws, size_t ws_size,
                              hipStream_t stream)
{
    (void)in_sizes; (void)n_in; (void)out_size;
    const float* x    = (const float*)d_in[0];
    const float* dxp  = (const float*)d_in[1];
    const float* bx   = (const float*)d_in[2];
    const float* sx   = (const float*)d_in[3];
    const float* d3   = (const float*)d_in[4];
    const float* W_ii = (const float*)d_in[9];
    const float* W_if = (const float*)d_in[10];
    const float* W_ig = (const float*)d_in[11];
    const float* W_io = (const float*)d_in[12];
    const float* W_hi = (const float*)d_in[13];
    const float* W_hf = (const float*)d_in[14];
    const float* W_hg = (const float*)d_in[15];
    const float* W_ho = (const float*)d_in[16];
    const float* b_ii = (const float*)d_in[17];
    const float* b_if = (const float*)d_in[18];
    const float* b_ig = (const float*)d_in[19];
    const float* b_io = (const float*)d_in[20];
    const float* b_hi = (const float*)d_in[21];
    const float* b_hf = (const float*)d_in[22];
    const float* b_hg = (const float*)d_in[23];
    const float* b_ho = (const float*)d_in[24];
    const float* W_y  = (const float*)d_in[25];
    const float* b_y  = (const float*)d_in[26];
    const float* W_d  = (const float*)d_in[27];
    const float* b_d  = (const float*)d_in[28];
    const float* W_g  = (const float*)d_in[29];
    const float* b_g  = (const float*)d_in[30];
    const float* W_ic = (const float*)d_in[31];
    const float* W_hc = (const float*)d_in[32];
    const float* W_pc = (const float*)d_in[33];
    const float* b_ic = (const float*)d_in[34];
    const float* b_hc = (const float*)d_in[35];
    const float* b_pc = (const float*)d_in[36];
    const float* W_k  = (const float*)d_in[37];
    const float* b_k  = (const float*)d_in[38];
    const float* emb  = (const float*)d_in[39];
    const float* gam  = (const float*)d_in[40];
    const float* bet  = (const float*)d_in[41];
    float* out = (float*)d_out;

    char* base = (char*)d_ws;
    size_t off = 0;
    auto take = [&](size_t bytes) -> char* {
        char* p = base + off;
        off = (off + bytes + 255) & ~(size_t)255;
        return p;
    };
    ushort_t* Wx    = (ushort_t*)take((size_t)1280 * 128 * 2);
    ushort_t* Wg    = (ushort_t*)take((size_t)256 * 128 * 2);
    ushort_t* Wh    = (ushort_t*)take((size_t)1536 * 256 * 2);
    float*    bias5 = (float*)take(1280 * 4);
    ushort_t* hM    = (ushort_t*)take((size_t)65536 * 2);
    float*    cM    = (float*)take((size_t)65536 * 4);
    float*    hsM   = (float*)take((size_t)65536 * 4);
    size_t fixedOff = off;

    // per-step chunk bytes: XB 65536 + IB 65536 + PB 10240 + g2B 1024 + S 1048576
    int C = 512;
    while (C > 4) {
        size_t need = fixedOff + (size_t)C * (65536 + 65536 + 10240 + 1024 + 1048576) + 6 * 256;
        if (need <= ws_size) break;
        C >>= 1;
    }
    ushort_t* XB  = (ushort_t*)take((size_t)C * 65536);
    ushort_t* IB  = (ushort_t*)take((size_t)C * 65536);
    ushort_t* PB  = (ushort_t*)take((size_t)C * 10240);
    float*    g2B = (float*)take((size_t)C * 1024);
    ushort_t* S   = (ushort_t*)take((size_t)C * 1048576);

    prep_kernel<<<1536, 256, 0, stream>>>(
        W_ii, W_if, W_ig, W_io, W_ic, W_g, W_hi, W_hf, W_hg, W_ho, W_hc, W_d,
        b_ii, b_if, b_ig, b_io, b_hi, b_hf, b_hg, b_ho, b_ic, b_hc,
        Wx, Wg, Wh, bias5);
    ont_kernel<<<1, 64, 0, stream>>>(emb, out + 256);
    init_kernel<<<256, 256, 0, stream>>>(hM, cM, hsM);

    for (int T0 = 0; T0 < TSZ; T0 += C) {
        trans_kernel<<<C * 256, 128, 0, stream>>>(x, dxp, bx, d3, XB, IB, PB, g2B, T0);
        small_kernel<<<C * 256, 64, 0, stream>>>(PB, emb, W_k, b_k, W_pc, b_pc, S, out + 276, T0);
        gemmA_kernel<<<dim3(12, C * 2), 256, 0, stream>>>(Wx, Wg, XB, IB, bias5, b_g, S);
        phaseB_kernel<<<16, 512, 0, stream>>>(Wh, S, g2B, b_d, hM, cM, hsM, C);
    }
    head_kernel<<<1, 256, 0, stream>>>(W_y, b_y, sx, hsM, gam, bet, out);
}

// Round 5
// 3710.732 us; speedup vs baseline: 4.1706x; 2.8302x over previous
//
#include <hip/hip_runtime.h>

// ---------------------------------------------------------------------------
// KIT-LSTM  (BS=256, TS=512, I=128, H=256, S=32, ONT=20)
//
// Phase A (parallel): transpose + precompute 8 bf16 "streams" per (t,b).
// Phase B (sequential): 128 WGs (16 groups x 8 workers), 1 WG/CU. Worker j
//   of group g holds rows [32j,32j+32) of all 6 W_h gates in LDS (98KB,
//   loaded once) and computes those rows' preacts for the group's 16 batch
//   columns. Per step only h,c (8KB bf16 each) are exchanged through
//   double-buffered global buffers + one group barrier (device-scope
//   atomics); combine is worker-local.
// Head: W_y @ [h_sum; static] -> batchnorm over batch -> sigmoid.
// ---------------------------------------------------------------------------

typedef float        f32x4  __attribute__((ext_vector_type(4)));
typedef short        bf16x8 __attribute__((ext_vector_type(8)));
typedef unsigned short u16x4 __attribute__((ext_vector_type(4)));
typedef unsigned short ushort_t;

#define HD   256
#define BSZ  256
#define TSZ  512
#define IDIM 128
#define NONT 20

__device__ __forceinline__ float b2f(ushort_t u) {
    unsigned int v = ((unsigned int)u) << 16;
    float f; __builtin_memcpy(&f, &v, 4); return f;
}
__device__ __forceinline__ ushort_t f2b(float f) {
    unsigned int v; __builtin_memcpy(&v, &f, 4);
    unsigned int r = (v + 0x7FFFu + ((v >> 16) & 1u)) >> 16;   // RNE
    return (ushort_t)r;
}
__device__ __forceinline__ float rcp_fast(float x) { return __builtin_amdgcn_rcpf(x); }
__device__ __forceinline__ float sigf(float x) { return rcp_fast(1.f + __expf(-x)); }
// tanh(x) = 1 - 2/(e^{2x}+1); overflow-safe (inf -> 1, -inf -> -1)
__device__ __forceinline__ float tanh_f(float x) {
    return __builtin_fmaf(-2.f, rcp_fast(__expf(2.f * x) + 1.f), 1.f);
}

// ---------------------------------------------------------------------------
// prep: cast/concat weights to bf16, merge bias pairs.
//   Wx [1280][128] rows = {W_ii,W_if,W_ig,W_io,W_ic}; Wg [256][128]
//   Wh [1536][256] rows = {W_hi,W_hf,W_hg,W_ho,W_hc,W_d}
//   bias5[1280] = b_i* + b_h*
// ---------------------------------------------------------------------------
__global__ void prep_kernel(
    const float* __restrict__ W_ii, const float* __restrict__ W_if,
    const float* __restrict__ W_ig, const float* __restrict__ W_io,
    const float* __restrict__ W_ic, const float* __restrict__ W_gm,
    const float* __restrict__ W_hi, const float* __restrict__ W_hf,
    const float* __restrict__ W_hg, const float* __restrict__ W_ho,
    const float* __restrict__ W_hc, const float* __restrict__ W_dm,
    const float* __restrict__ b_ii, const float* __restrict__ b_if,
    const float* __restrict__ b_ig, const float* __restrict__ b_io,
    const float* __restrict__ b_hi, const float* __restrict__ b_hf,
    const float* __restrict__ b_hg, const float* __restrict__ b_ho,
    const float* __restrict__ b_ic, const float* __restrict__ b_hc,
    ushort_t* __restrict__ Wx, ushort_t* __restrict__ Wg,
    ushort_t* __restrict__ Wh, float* __restrict__ bias5)
{
    const int i = blockIdx.x * 256 + threadIdx.x;
    if (i < 1280 * IDIM) {
        int m = i >> 7, k = i & 127, g = m >> 8, rr = m & 255;
        const float* src = (g == 0) ? W_ii : (g == 1) ? W_if : (g == 2) ? W_ig : (g == 3) ? W_io : W_ic;
        Wx[i] = f2b(src[rr * IDIM + k]);
    }
    if (i < 256 * IDIM) Wg[i] = f2b(W_gm[i]);
    if (i < 1536 * HD) {
        int m = i >> 8, k = i & 255, g = m >> 8, rr = m & 255;
        const float* src = (g == 0) ? W_hi : (g == 1) ? W_hf : (g == 2) ? W_hg
                          : (g == 3) ? W_ho : (g == 4) ? W_hc : W_dm;
        Wh[i] = f2b(src[rr * HD + k]);
    }
    if (i < 1280) {
        int g = i >> 8, rr = i & 255;
        const float* sa = (g == 0) ? b_ii : (g == 1) ? b_if : (g == 2) ? b_ig : (g == 3) ? b_io : b_ic;
        const float* sb = (g == 0) ? b_hi : (g == 1) ? b_hf : (g == 2) ? b_hg : (g == 3) ? b_ho : b_hc;
        bias5[i] = sa[rr] + sb[rr];
    }
}

// ---------------------------------------------------------------------------
// init: c = 1 (f32), h_sum = 0, h/c broadcast buffers = 1.0 bf16 (both
// parities), group barrier counters = 0.
// ---------------------------------------------------------------------------
__global__ void init_kernel(float* __restrict__ cM, float* __restrict__ hsM,
                            ushort_t* __restrict__ hbuf, ushort_t* __restrict__ cbuf,
                            unsigned* __restrict__ bar)
{
    const int i = blockIdx.x * 256 + threadIdx.x;   // 65536
    cM[i] = 1.f;
    hsM[i] = 0.f;
    hbuf[i] = 0x3F80; hbuf[i + 65536] = 0x3F80;
    cbuf[i] = 0x3F80; cbuf[i + 65536] = 0x3F80;
    if (i < 16) bar[i * 32] = 0u;
}

// ---------------------------------------------------------------------------
// ont_dist_normed = softmax(|ent - tgt|) -> out[256..276)
// ---------------------------------------------------------------------------
__global__ void ont_kernel(const float* __restrict__ emb, float* __restrict__ o)
{
    __shared__ float dS[NONT];
    const int L = threadIdx.x;
    if (L < NONT) dS[L] = fabsf(emb[L] - emb[NONT]);
    __syncthreads();
    if (L < NONT) {
        float mx = dS[0];
        for (int k = 1; k < NONT; ++k) mx = fmaxf(mx, dS[k]);
        float s = 0.f;
        for (int k = 0; k < NONT; ++k) s += __expf(dS[k] - mx);
        o[L] = __expf(dS[L] - mx) / s;
    }
}

// ---------------------------------------------------------------------------
// transpose/precompute per chunk: n = t_local*256 + b
// ---------------------------------------------------------------------------
__global__ void trans_kernel(
    const float* __restrict__ x, const float* __restrict__ dx,
    const float* __restrict__ bx, const float* __restrict__ d3,
    ushort_t* __restrict__ XB, ushort_t* __restrict__ IB,
    ushort_t* __restrict__ PB, float* __restrict__ g2B, int T0)
{
    const int n = blockIdx.x;
    const int t = n >> 8, b = n & 255;
    const int k = threadIdx.x;                       // 128
    const size_t src = ((size_t)b * TSZ + (T0 + t)) * IDIM + k;
    XB[n * IDIM + k] = f2b(x[src]);
    IB[n * IDIM + k] = f2b(1.f + __expf(-dx[src]));
    if (k < NONT) PB[n * NONT + k] = f2b(bx[((size_t)b * TSZ + (T0 + t)) * NONT + k]);
    if (k == 0) g2B[n] = sigf(1.f / d3[(size_t)b * TSZ + (T0 + t)]);
}

// ---------------------------------------------------------------------------
// small mats: per n: a = softmax(ent*p) -> output3;  S[g6] = sigmoid(W_k@a+b_k)
//   S[g7] = W_pc@p + b_pc.   S layout: (((t*8+g)*256 + b)*256 + r), bf16.
// ---------------------------------------------------------------------------
__global__ void small_kernel(
    const ushort_t* __restrict__ PB, const float* __restrict__ emb,
    const float* __restrict__ W_k, const float* __restrict__ b_k,
    const float* __restrict__ W_pc, const float* __restrict__ b_pc,
    ushort_t* __restrict__ S, float* __restrict__ aout, int T0)
{
    const int n = blockIdx.x;
    const int t = n >> 8, b = n & 255;
    const int L = threadIdx.x;                        // 64
    __shared__ float pS[NONT], aS[NONT];
    if (L < NONT) pS[L] = b2f(PB[n * NONT + L]);
    __syncthreads();
    if (L < NONT) aS[L] = emb[L] * pS[L];
    __syncthreads();
    float aval = 0.f;
    {
        float mx = aS[0];
        #pragma unroll
        for (int k = 1; k < NONT; ++k) mx = fmaxf(mx, aS[k]);
        float sum = 0.f;
        #pragma unroll
        for (int k = 0; k < NONT; ++k) sum += __expf(aS[k] - mx);
        if (L < NONT) aval = __expf(aS[L] - mx) / sum;
    }
    __syncthreads();
    if (L < NONT) {
        aS[L] = aval;
        aout[(size_t)L * (TSZ * BSZ) + (size_t)T0 * BSZ + n] = aval;
    }
    __syncthreads();
    #pragma unroll
    for (int j = 0; j < 4; ++j) {
        int rr = j * 64 + L;
        float accK = b_k[rr], accP = b_pc[rr];
        #pragma unroll
        for (int k = 0; k < NONT; ++k) {
            accK += W_k[rr * NONT + k] * aS[k];
            accP += W_pc[rr * NONT + k] * pS[k];
        }
        S[(((size_t)t * 8 + 6) * 256 + b) * 256 + rr] = f2b(sigf(accK));
        S[(((size_t)t * 8 + 7) * 256 + b) * 256 + rr] = f2b(accP);
    }
}

// ---------------------------------------------------------------------------
// Phase-A GEMM: 128x128 tiles, bf16 MFMA 16x16x32, K=128.
// ---------------------------------------------------------------------------
__launch_bounds__(256)
__global__ void gemmA_kernel(
    const ushort_t* __restrict__ Wx, const ushort_t* __restrict__ Wg,
    const ushort_t* __restrict__ XB, const ushort_t* __restrict__ IB,
    const float* __restrict__ bias5, const float* __restrict__ b_g,
    ushort_t* __restrict__ S)
{
    const int mt = blockIdx.x;                 // 0..11
    const int nt = blockIdx.y;                 // 0..2C-1
    const bool isG = (mt >= 10);
    const ushort_t* A = isG ? (Wg + (size_t)(mt - 10) * 128 * IDIM)
                            : (Wx + (size_t)mt * 128 * IDIM);
    const ushort_t* B = (isG ? IB : XB) + (size_t)nt * 128 * IDIM;

    __shared__ ushort_t Asm[128 * 128];
    __shared__ ushort_t Bsm[128 * 128];

    const int tid = threadIdx.x;
    const int lane = tid & 63, w = tid >> 6;
    const int l15 = lane & 15, l4 = lane >> 4;

    {
        const int4* As = (const int4*)A;
        const int4* Bs = (const int4*)B;
        int4* Ad = (int4*)Asm;
        int4* Bd = (int4*)Bsm;
        #pragma unroll
        for (int c = 0; c < 8; ++c) {
            int idx = c * 256 + tid;               // 0..2047 (16B units)
            int row = idx >> 4, kb = idx & 15;
            int didx = row * 16 + (kb ^ (row & 7));
            Ad[didx] = As[idx];
            Bd[didx] = Bs[idx];
        }
    }
    __syncthreads();

    const int wm = (w >> 1) * 64, wn = (w & 1) * 64;
    f32x4 acc[4][4];
    #pragma unroll
    for (int i = 0; i < 4; ++i) {
        #pragma unroll
        for (int j = 0; j < 4; ++j) acc[i][j] = (f32x4){0.f, 0.f, 0.f, 0.f};
    }

    #pragma unroll
    for (int ks = 0; ks < 4; ++ks) {
        bf16x8 af[4], bfr[4];
        #pragma unroll
        for (int fi = 0; fi < 4; ++fi) {
            int rowA = wm + fi * 16 + l15;
            af[fi] = ((const bf16x8*)Asm)[rowA * 16 + ((ks * 4 + l4) ^ (rowA & 7))];
            int rowB = wn + fi * 16 + l15;
            bfr[fi] = ((const bf16x8*)Bsm)[rowB * 16 + ((ks * 4 + l4) ^ (rowB & 7))];
        }
        #pragma unroll
        for (int fi = 0; fi < 4; ++fi) {
            #pragma unroll
            for (int fj = 0; fj < 4; ++fj)
                acc[fi][fj] = __builtin_amdgcn_mfma_f32_16x16x32_bf16(af[fi], bfr[fj], acc[fi][fj], 0, 0, 0);
        }
    }

    // epilogue: C row = (lane>>4)*4 + i, col = lane&15  (m89-verified)
    const int t = nt >> 1;
    const int bbase = (nt & 1) * 128 + wn;
    #pragma unroll
    for (int fi = 0; fi < 4; ++fi) {
        #pragma unroll
        for (int fj = 0; fj < 4; ++fj) {
            int b = bbase + fj * 16 + l15;
            int mrow = wm + fi * 16 + l4 * 4;
            float v[4];
            int gate, rr;
            if (!isG) {
                int m = mt * 128 + mrow;
                gate = m >> 8; rr = m & 255;
                #pragma unroll
                for (int i = 0; i < 4; ++i) v[i] = acc[fi][fj][i] + bias5[m + i];
            } else {
                rr = (mt - 10) * 128 + mrow;
                gate = 5;
                #pragma unroll
                for (int i = 0; i < 4; ++i) v[i] = sigf(acc[fi][fj][i] + b_g[rr + i]);
            }
            u16x4 pk;
            #pragma unroll
            for (int i = 0; i < 4; ++i) pk[i] = f2b(v[i]);
            *(u16x4*)&S[(((size_t)t * 8 + gate) * 256 + b) * 256 + rr] = pk;
        }
    }
}

// ---------------------------------------------------------------------------
// Phase B: 128 WGs x 256 threads. group g = bid&15 (16 batch cols each),
// worker j = bid>>4 (rows [32j,32j+32) of all 6 gates). W slice in LDS.
// Per step: MFMA (12 tiles 16x16, K=256, B = h/c bf16 in LDS) -> P exchange
// (LDS) -> worker-local combine -> h/c slice store (agent atomics, parity
// buffer) -> group barrier (monotonic counter) -> read back full h/c.
// ---------------------------------------------------------------------------
__launch_bounds__(256, 1)
__global__ void phaseB_kernel(
    const ushort_t* __restrict__ Wh, const ushort_t* __restrict__ S,
    const float* __restrict__ g2B, const float* __restrict__ b_d,
    float* __restrict__ cM, float* __restrict__ hsM,
    ushort_t* __restrict__ hbuf, ushort_t* __restrict__ cbuf,
    unsigned* __restrict__ bar, int C, int T0)
{
    __shared__ ushort_t Wl[192 * 256];      // 98304 B, 16B-granule XOR swizzle
    __shared__ ushort_t hB[16 * 256];       // [col][k] swizzled, 8KB
    __shared__ ushort_t cB[16 * 256];
    __shared__ float    P[192 * 17];        // preact exchange, 13KB

    const int tid = threadIdx.x;            // 0..255
    const int lane = tid & 63, w = tid >> 6;   // 4 waves
    const int l15 = lane & 15, l4 = lane >> 4;
    const int g = blockIdx.x & 15;          // group (workers share XCD mod-8)
    const int j = blockIdx.x >> 4;          // worker 0..7
    const int b0 = g * 16;

    // ---- stage W slice: rows gate*256 + j*32 + rloc, swizzled LDS ----
    #pragma unroll 4
    for (int it = 0; it < 24; ++it) {
        int gi = it * 256 + tid;            // 16B granule 0..6143
        int m = gi >> 5, kb = gi & 31;      // local row m 0..191
        int grow = (m >> 5) * 256 + j * 32 + (m & 31);
        const int4 v = *(const int4*)(Wh + (size_t)grow * HD + kb * 8);
        *(int4*)&Wl[(m * 32 + (kb ^ (m & 7))) * 8] = v;
    }

    // ---- combine-role mapping: col cc, row pair (rr, rr+1) ----
    const int cc = tid >> 4;                // 0..15
    const int rr = (tid & 15) * 2;          // 0..30
    const int gr0 = j * 32 + rr;            // H-row
    const float bd0 = b_d[gr0], bd1 = b_d[gr0 + 1];
    float c0 = cM[(size_t)(b0 + cc) * HD + gr0];
    float c1 = cM[(size_t)(b0 + cc) * HD + gr0 + 1];
    float hs0 = hsM[(size_t)gr0 * BSZ + b0 + cc];
    float hs1 = hsM[(size_t)(gr0 + 1) * BSZ + b0 + cc];

    // ---- initial h/c broadcast (parity 1 = state after step T0-1) ----
    {
        const unsigned* hsrc = (const unsigned*)(hbuf + 65536 + (size_t)g * 4096);
        const unsigned* csrc = (const unsigned*)(cbuf + 65536 + (size_t)g * 4096);
        #pragma unroll
        for (int k = 0; k < 8; ++k) {
            const unsigned u = k * 256 + tid;      // u32 index 0..2047
            unsigned hv = __hip_atomic_load(&hsrc[u], __ATOMIC_RELAXED, __HIP_MEMORY_SCOPE_AGENT);
            unsigned cv = __hip_atomic_load(&csrc[u], __ATOMIC_RELAXED, __HIP_MEMORY_SCOPE_AGENT);
            const int col = u >> 7, r2 = u & 127;
            const int di = (col * 32 + ((r2 >> 2) ^ (col & 7))) * 4 + (r2 & 3);
            ((unsigned*)hB)[di] = hv;
            ((unsigned*)cB)[di] = cv;
        }
    }
    __syncthreads();

    #pragma unroll 1
    for (int t = 0; t < C; ++t) {
        const int gstep = T0 + t;
        // ---- S prefetch (consumed after MFMA; latency hidden) ----
        unsigned sv[8];
        #pragma unroll
        for (int q = 0; q < 8; ++q)
            sv[q] = *(const unsigned*)(S + (((size_t)t * 8 + q) * 256 + b0 + cc) * 256 + gr0);
        const float g2v = g2B[t * BSZ + b0 + cc];

        // ---- MFMA: wave w owns tiles 3w..3w+2 (16 rows x 16 cols, K=256) ----
        f32x4 acc[3];
        #pragma unroll
        for (int q = 0; q < 3; ++q) acc[q] = (f32x4){0.f, 0.f, 0.f, 0.f};
        #pragma unroll
        for (int ks = 0; ks < 8; ++ks) {
            const int kb = ks * 4 + l4;
            const bf16x8 bh = *(const bf16x8*)&hB[(l15 * 32 + (kb ^ (l15 & 7))) * 8];
            const bf16x8 bc = *(const bf16x8*)&cB[(l15 * 32 + (kb ^ (l15 & 7))) * 8];
            #pragma unroll
            for (int q = 0; q < 3; ++q) {
                const int T = w * 3 + q;
                const int m = T * 16 + l15;
                const bf16x8 a = *(const bf16x8*)&Wl[(m * 32 + (kb ^ (m & 7))) * 8];
                acc[q] = __builtin_amdgcn_mfma_f32_16x16x32_bf16(
                    a, (T >= 10) ? bc : bh, acc[q], 0, 0, 0);
            }
        }
        // ---- preact exchange via LDS ----
        #pragma unroll
        for (int q = 0; q < 3; ++q) {
            const int T = w * 3 + q;
            #pragma unroll
            for (int i = 0; i < 4; ++i)
                P[(T * 16 + l4 * 4 + i) * 17 + l15] = acc[q][i];
        }
        __syncthreads();

        // ---- worker-local combine for rows (gr0, gr0+1), col cc ----
        float s_[8][2];
        #pragma unroll
        for (int q = 0; q < 8; ++q) {
            s_[q][0] = b2f((ushort_t)(sv[q] & 0xFFFF));
            s_[q][1] = b2f((ushort_t)(sv[q] >> 16));
        }
        float hn[2], cn[2];
        #pragma unroll
        for (int i = 0; i < 2; ++i) {
            const float pi  = P[(0 * 32 + rr + i) * 17 + cc];
            const float pf  = P[(1 * 32 + rr + i) * 17 + cc];
            const float pg  = P[(2 * 32 + rr + i) * 17 + cc];
            const float po  = P[(3 * 32 + rr + i) * 17 + cc];
            const float pkg = P[(4 * 32 + rr + i) * 17 + cc];
            const float pcs = P[(5 * 32 + rr + i) * 17 + cc];
            const float it   = sigf(s_[0][i] + pi);
            const float ft   = sigf(s_[1][i] + pf);
            const float cand = tanh_f(s_[2][i] + pg);
            const float ot   = sigf(s_[3][i] + po);
            const float kg   = tanh_f(s_[4][i] + s_[7][i] + pkg);
            const float cs   = tanh_f(pcs + ((i == 0) ? bd0 : bd1));
            const float cold = (i == 0) ? c0 : c1;
            const float cstar = (cold - cs) * s_[5][i] + cs * g2v;
            const float cnew  = ft * cstar + it * cand + s_[6][i] * kg;
            const float hnew  = ot * tanh_f(cnew);
            hn[i] = hnew; cn[i] = cnew;
        }
        c0 = cn[0]; c1 = cn[1];
        hs0 += hn[0]; hs1 += hn[1];

        // ---- publish h/c slice (parity gstep&1), coherent stores ----
        const int par = gstep & 1;
        const unsigned hp = (unsigned)f2b(hn[0]) | ((unsigned)f2b(hn[1]) << 16);
        const unsigned cp = (unsigned)f2b(cn[0]) | ((unsigned)f2b(cn[1]) << 16);
        unsigned* hd = (unsigned*)(hbuf + (size_t)par * 65536 + (size_t)g * 4096);
        unsigned* cd = (unsigned*)(cbuf + (size_t)par * 65536 + (size_t)g * 4096);
        const int ui = cc * 128 + (gr0 >> 1);
        __hip_atomic_store(&hd[ui], hp, __ATOMIC_RELAXED, __HIP_MEMORY_SCOPE_AGENT);
        __hip_atomic_store(&cd[ui], cp, __ATOMIC_RELAXED, __HIP_MEMORY_SCOPE_AGENT);
        __syncthreads();   // drains stores (vmcnt 0) + P consumed

        // ---- group barrier: monotonic counter, target 8*(gstep+1) ----
        if (tid == 0) {
            __hip_atomic_fetch_add(&bar[g * 32], 1u, __ATOMIC_RELEASE, __HIP_MEMORY_SCOPE_AGENT);
            const unsigned tgt = 8u * (unsigned)(gstep + 1);
            while (__hip_atomic_load(&bar[g * 32], __ATOMIC_ACQUIRE, __HIP_MEMORY_SCOPE_AGENT) < tgt)
                __builtin_amdgcn_s_sleep(2);
        }
        __syncthreads();

        // ---- read back full group h/c into LDS ----
        {
            const unsigned* hsrc = (const unsigned*)(hbuf + (size_t)par * 65536 + (size_t)g * 4096);
            const unsigned* csrc = (const unsigned*)(cbuf + (size_t)par * 65536 + (size_t)g * 4096);
            #pragma unroll
            for (int k = 0; k < 8; ++k) {
                const unsigned u = k * 256 + tid;
                unsigned hv = __hip_atomic_load(&hsrc[u], __ATOMIC_RELAXED, __HIP_MEMORY_SCOPE_AGENT);
                unsigned cv = __hip_atomic_load(&csrc[u], __ATOMIC_RELAXED, __HIP_MEMORY_SCOPE_AGENT);
                const int col = u >> 7, r2 = u & 127;
                const int di = (col * 32 + ((r2 >> 2) ^ (col & 7))) * 4 + (r2 & 3);
                ((unsigned*)hB)[di] = hv;
                ((unsigned*)cB)[di] = cv;
            }
        }
        __syncthreads();
    }

    // ---- persist per-worker state for next chunk / head ----
    cM[(size_t)(b0 + cc) * HD + gr0]     = c0;
    cM[(size_t)(b0 + cc) * HD + gr0 + 1] = c1;
    hsM[(size_t)gr0 * BSZ + b0 + cc]       = hs0;
    hsM[(size_t)(gr0 + 1) * BSZ + b0 + cc] = hs1;
}

// ---------------------------------------------------------------------------
// head: out[b] = W_y @ [h_sum[:,b]; static[b,:]] + b_y -> batchnorm -> sigmoid
// ---------------------------------------------------------------------------
__global__ void head_kernel(
    const float* __restrict__ W_y, const float* __restrict__ b_y,
    const float* __restrict__ sx, const float* __restrict__ hsM,
    const float* __restrict__ gamma, const float* __restrict__ beta,
    float* __restrict__ yout)
{
    const int b = threadIdx.x;   // 256
    float acc = b_y[0];
    for (int rr = 0; rr < HD; ++rr) acc += W_y[rr] * hsM[rr * BSZ + b];
    #pragma unroll
    for (int s = 0; s < 32; ++s) acc += W_y[HD + s] * sx[b * 32 + s];

    __shared__ float red[256];
    red[b] = acc; __syncthreads();
    for (int st = 128; st > 0; st >>= 1) {
        if (b < st) red[b] += red[b + st];
        __syncthreads();
    }
    float mean = red[0] * (1.f / 256.f);
    __syncthreads();
    float d = acc - mean;
    red[b] = d * d; __syncthreads();
    for (int st = 128; st > 0; st >>= 1) {
        if (b < st) red[b] += red[b + st];
        __syncthreads();
    }
    float var = red[0] * (1.f / 256.f);
    yout[b] = sigf(d * rsqrtf(var + 1e-5f) * gamma[0] + beta[0]);
}

// ---------------------------------------------------------------------------
extern "C" void kernel_launch(void* const* d_in, const int* in_sizes, int n_in,
                              void* d_out, int out_size, void* d_ws, size_t ws_size,
                              hipStream_t stream)
{
    (void)in_sizes; (void)n_in; (void)out_size;
    const float* x    = (const float*)d_in[0];
    const float* dxp  = (const float*)d_in[1];
    const float* bx   = (const float*)d_in[2];
    const float* sx   = (const float*)d_in[3];
    const float* d3   = (const float*)d_in[4];
    const float* W_ii = (const float*)d_in[9];
    const float* W_if = (const float*)d_in[10];
    const float* W_ig = (const float*)d_in[11];
    const float* W_io = (const float*)d_in[12];
    const float* W_hi = (const float*)d_in[13];
    const float* W_hf = (const float*)d_in[14];
    const float* W_hg = (const float*)d_in[15];
    const float* W_ho = (const float*)d_in[16];
    const float* b_ii = (const float*)d_in[17];
    const float* b_if = (const float*)d_in[18];
    const float* b_ig = (const float*)d_in[19];
    const float* b_io = (const float*)d_in[20];
    const float* b_hi = (const float*)d_in[21];
    const float* b_hf = (const float*)d_in[22];
    const float* b_hg = (const float*)d_in[23];
    const float* b_ho = (const float*)d_in[24];
    const float* W_y  = (const float*)d_in[25];
    const float* b_y  = (const float*)d_in[26];
    const float* W_d  = (const float*)d_in[27];
    const float* b_d  = (const float*)d_in[28];
    const float* W_g  = (const float*)d_in[29];
    const float* b_g  = (const float*)d_in[30];
    const float* W_ic = (const float*)d_in[31];
    const float* W_hc = (const float*)d_in[32];
    const float* W_pc = (const float*)d_in[33];
    const float* b_ic = (const float*)d_in[34];
    const float* b_hc = (const float*)d_in[35];
    const float* b_pc = (const float*)d_in[36];
    const float* W_k  = (const float*)d_in[37];
    const float* b_k  = (const float*)d_in[38];
    const float* emb  = (const float*)d_in[39];
    const float* gam  = (const float*)d_in[40];
    const float* bet  = (const float*)d_in[41];
    float* out = (float*)d_out;

    char* base = (char*)d_ws;
    size_t off = 0;
    auto take = [&](size_t bytes) -> char* {
        char* p = base + off;
        off = (off + bytes + 255) & ~(size_t)255;
        return p;
    };
    ushort_t* Wx    = (ushort_t*)take((size_t)1280 * 128 * 2);
    ushort_t* Wg    = (ushort_t*)take((size_t)256 * 128 * 2);
    ushort_t* Wh    = (ushort_t*)take((size_t)1536 * 256 * 2);
    float*    bias5 = (float*)take(1280 * 4);
    float*    cM    = (float*)take((size_t)65536 * 4);
    float*    hsM   = (float*)take((size_t)65536 * 4);
    ushort_t* hbuf  = (ushort_t*)take((size_t)2 * 65536 * 2);
    ushort_t* cbuf  = (ushort_t*)take((size_t)2 * 65536 * 2);
    unsigned* bar   = (unsigned*)take(16 * 32 * 4);
    size_t fixedOff = off;

    // per-step chunk bytes: XB 65536 + IB 65536 + PB 10240 + g2B 1024 + S 1048576
    int C = 512;
    while (C > 4) {
        size_t need = fixedOff + (size_t)C * (65536 + 65536 + 10240 + 1024 + 1048576) + 6 * 256;
        if (need <= ws_size) break;
        C >>= 1;
    }
    ushort_t* XB  = (ushort_t*)take((size_t)C * 65536);
    ushort_t* IB  = (ushort_t*)take((size_t)C * 65536);
    ushort_t* PB  = (ushort_t*)take((size_t)C * 10240);
    float*    g2B = (float*)take((size_t)C * 1024);
    ushort_t* S   = (ushort_t*)take((size_t)C * 1048576);

    prep_kernel<<<1536, 256, 0, stream>>>(
        W_ii, W_if, W_ig, W_io, W_ic, W_g, W_hi, W_hf, W_hg, W_ho, W_hc, W_d,
        b_ii, b_if, b_ig, b_io, b_hi, b_hf, b_hg, b_ho, b_ic, b_hc,
        Wx, Wg, Wh, bias5);
    ont_kernel<<<1, 64, 0, stream>>>(emb, out + 256);
    init_kernel<<<256, 256, 0, stream>>>(cM, hsM, hbuf, cbuf, bar);

    for (int T0 = 0; T0 < TSZ; T0 += C) {
        trans_kernel<<<C * 256, 128, 0, stream>>>(x, dxp, bx, d3, XB, IB, PB, g2B, T0);
        small_kernel<<<C * 256, 64, 0, stream>>>(PB, emb, W_k, b_k, W_pc, b_pc, S, out + 276, T0);
        gemmA_kernel<<<dim3(12, C * 2), 256, 0, stream>>>(Wx, Wg, XB, IB, bias5, b_g, S);
        phaseB_kernel<<<128, 256, 0, stream>>>(Wh, S, g2B, b_d, cM, hsM, hbuf, cbuf, bar, C, T0);
    }
    head_kernel<<<1, 256, 0, stream>>>(W_y, b_y, sx, hsM, gam, bet, out);
}